// Round 5
// baseline (2854.791 us; speedup 1.0000x reference)
//
#include <hip/hip_runtime.h>

#define LAYERS 4
#define BATCH  64
#define SEQ    256
#define HID    1024

typedef _Float16 half8 __attribute__((ext_vector_type(8)));
typedef _Float16 half4 __attribute__((ext_vector_type(4)));
typedef float    f32x4 __attribute__((ext_vector_type(4)));
typedef unsigned long long u64;

__device__ __forceinline__ float sig_(float x) { return 1.0f / (1.0f + __expf(-x)); }
__device__ __forceinline__ float th_(float x)  { return 2.0f / (1.0f + __expf(-2.0f * x)) - 1.0f; }

// sc1 (LLC-coherent) store: relaxed agent-scope atomic -> write-through to the
// Infinity Cache (coherence point), bypassing the non-coherent per-XCD L2.
__device__ __forceinline__ void llc_store_h4(_Float16* p, half4 v) {
    union { half4 h; u64 u; } cv; cv.h = v;
    __hip_atomic_store((u64*)p, cv.u, __ATOMIC_RELAXED, __HIP_MEMORY_SCOPE_AGENT);
}

// Per-layer dataflow sync state (each field on its own 64B line).
struct BarSt {
    int arrive[LAYERS][16];   // monotonic arrival counters (64 blocks/layer)
    int done[LAYERS][16];     // done[l] = number of completed time-steps of layer l
};

__global__ void k_bias(const float* __restrict__ bih, const float* __restrict__ bhh,
                       float* __restrict__ bias) {
    int i = blockIdx.x * blockDim.x + threadIdx.x;
    if (i < LAYERS * 4 * HID) bias[i] = bih[i] + bhh[i];
}

// Pack weights fp32 -> f16, gate-major per-wave fragment order.
__global__ void k_packw(const float* __restrict__ wih32, const float* __restrict__ whh32,
                        _Float16* __restrict__ wpack) {
    unsigned c = blockIdx.x * blockDim.x + threadIdx.x;   // < 2^22
    int lane = c & 63, g = (c >> 6) & 3, il = (c >> 8) & 7, q = (c >> 11) & 3;
    int jblk = (c >> 13) & 63, kh = (c >> 19) & 1, l = (int)(c >> 20);
    const float* src = (kh ? whh32 : wih32)
        + ((size_t)l * 4 * HID + (size_t)g * HID + jblk * 16 + (lane & 15)) * HID
        + (q * 8 + il) * 32 + (lane >> 4) * 8;
    f32x4 a = *(const f32x4*)src;
    f32x4 b = *(const f32x4*)(src + 4);
    half8 d;
    d[0]=(_Float16)a[0]; d[1]=(_Float16)a[1]; d[2]=(_Float16)a[2]; d[3]=(_Float16)a[3];
    d[4]=(_Float16)b[0]; d[5]=(_Float16)b[1]; d[6]=(_Float16)b[2]; d[7]=(_Float16)b[3];
    *(half8*)(wpack + (size_t)c * 8) = d;
}

// Pack x fp32 [B,T,H] -> f16 fragment order per t.
__global__ void k_packx(const float* __restrict__ x32, _Float16* __restrict__ xpack) {
    unsigned c = blockIdx.x * blockDim.x + threadIdx.x;   // < 2^21
    int lane = c & 63, i = (c >> 6) & 31, mt = (c >> 11) & 3, t = (int)(c >> 13);
    int m = mt * 16 + (lane & 15);
    int k = i * 32 + (lane >> 4) * 8;
    const float* src = x32 + ((size_t)m * SEQ + t) * HID + k;
    f32x4 a = *(const f32x4*)src;
    f32x4 b = *(const f32x4*)(src + 4);
    half8 d;
    d[0]=(_Float16)a[0]; d[1]=(_Float16)a[1]; d[2]=(_Float16)a[2]; d[3]=(_Float16)a[3];
    d[4]=(_Float16)b[0]; d[5]=(_Float16)b[1]; d[6]=(_Float16)b[2]; d[7]=(_Float16)b[3];
    *(half8*)(xpack + (size_t)c * 8) = d;
}

// ---------------------------------------------------------------------------
// Persistent kernel, per-layer dataflow sync (no global lockstep):
//  - weights in registers for the whole sequence; c-state + bias in LDS
//  - h slabs WRITE-ONCE: hfull[t*L + l + 1] (slot 0 = zeros); writers sc1-store
//    (write-through to IF), readers use plain L2-cached 16B loads (no address
//    is ever written twice in a run -> no stale L2 line possible)
//  - kh=0 waves wait only on done[l-1] >= t+1; kh=1 waves wait only on
//    done[l] >= t. Own-layer sync latency hides under kh=0's load+MFMA work.
// 256 blocks (1/CU) x 512 threads: layer = bid>>6, 16 cols; wave = (kh, q).
// ---------------------------------------------------------------------------
__global__ __launch_bounds__(512, 1) void k_persist(
        const _Float16* __restrict__ xpack,
        const _Float16* __restrict__ wpack,
        const float*    __restrict__ bih,
        const float*    __restrict__ bhh,
        _Float16*       __restrict__ hfull,  // [SEQ*L+1][BH] f16, fragment order
        BarSt*          __restrict__ bar,
        float*          __restrict__ out)    // [B, H] fp32
{
    const int layer = blockIdx.x >> 6;
    const int jblk  = blockIdx.x & 63;
    const int j0    = jblk << 4;
    const int tid   = threadIdx.x;
    const int wave  = tid >> 6;
    const int q     = wave & 3;
    const int kh    = wave >> 2;
    const int lane  = tid & 63;
    const int nl    = lane & 15;
    const int quad  = lane >> 4;
    const size_t BH = (size_t)BATCH * HID;

    __shared__ __align__(16) float gplane[4][4][32][20];   // padded: 2-way max
    __shared__ __align__(16) float cbuf[64][16];           // cell state
    __shared__ __align__(16) float gbias[4][16];           // bih+bhh slice

    for (int i = tid; i < 64 * 16; i += 512) ((float*)cbuf)[i] = 0.0f;
    if (tid < 64) {
        int g = tid >> 4, col = tid & 15;
        size_t bidx = (size_t)layer * 4 * HID + (size_t)g * HID + j0 + col;
        gbias[g][col] = bih[bidx] + bhh[bidx];
    }

    // weights -> registers, once (8 il x 4 gates x half8 = 128 regs/lane)
    const _Float16* Wp = wpack
        + ((((size_t)layer * 2 + kh) * 64 + jblk) * 4 + q) * 16384
        + (size_t)lane * 8;
    half8 wreg[8][4];
    #pragma unroll
    for (int il = 0; il < 8; ++il)
        #pragma unroll
        for (int g = 0; g < 4; ++g)
            wreg[il][g] = *(const half8*)(Wp + il * 2048 + g * 512);

    __syncthreads();

    const bool lastlayer = (layer == LAYERS - 1);

    for (int t = 0; t < SEQ; ++t) {
        // ---- wave-granularity dataflow waits ----
        if (lane == 0) {
            if (kh == 0) {
                if (layer > 0) {
                    while (__hip_atomic_load(&bar->done[layer - 1][0], __ATOMIC_RELAXED,
                                             __HIP_MEMORY_SCOPE_AGENT) < t + 1)
                        __builtin_amdgcn_s_sleep(1);
                }
            } else {
                if (t > 0) {
                    while (__hip_atomic_load(&bar->done[layer][0], __ATOMIC_RELAXED,
                                             __HIP_MEMORY_SCOPE_AGENT) < t)
                        __builtin_amdgcn_s_sleep(1);
                }
            }
        }
        __builtin_amdgcn_sched_barrier(0);
        asm volatile("" ::: "memory");

        // A operand base (fragment-packed), this wave's K-quarter
        const _Float16* Abase;
        if (kh == 0) {
            Abase = (layer == 0)
                ? (xpack + (size_t)t * BH)
                : (hfull + ((size_t)t * LAYERS + layer) * BH);       // (l-1, t)
        } else {
            Abase = hfull + (t == 0 ? (size_t)0
                                    : ((size_t)(t - 1) * LAYERS + layer + 1)) * BH;
        }
        const _Float16* Ap = Abase + (size_t)q * 4096 + (size_t)lane * 8;

        f32x4 acc[4][4];   // [mt][g]
        #pragma unroll
        for (int mt = 0; mt < 4; ++mt)
            #pragma unroll
            for (int g = 0; g < 4; ++g) acc[mt][g] = (f32x4){0,0,0,0};

        #pragma unroll
        for (int il = 0; il < 8; ++il) {
            #pragma unroll
            for (int mt = 0; mt < 4; ++mt) {
                half8 a = *(const half8*)(Ap + (size_t)mt * 16384 + il * 512);
                acc[mt][0] = __builtin_amdgcn_mfma_f32_16x16x32_f16(a, wreg[il][0], acc[mt][0], 0,0,0);
                acc[mt][1] = __builtin_amdgcn_mfma_f32_16x16x32_f16(a, wreg[il][1], acc[mt][1], 0,0,0);
                acc[mt][2] = __builtin_amdgcn_mfma_f32_16x16x32_f16(a, wreg[il][2], acc[mt][2], 0,0,0);
                acc[mt][3] = __builtin_amdgcn_mfma_f32_16x16x32_f16(a, wreg[il][3], acc[mt][3], 0,0,0);
            }
        }

        _Float16* hp = hfull + ((size_t)t * LAYERS + layer + 1) * BH;
        const bool last = lastlayer && (t == SEQ - 1);

        #pragma unroll
        for (int half = 0; half < 2; ++half) {
            // phase A: kh=1 waves deposit partials
            if (kh == 1) {
                #pragma unroll
                for (int mtl = 0; mtl < 2; ++mtl)
                    #pragma unroll
                    for (int g = 0; g < 4; ++g)
                        #pragma unroll
                        for (int r = 0; r < 4; ++r)
                            gplane[q][g][mtl * 16 + quad * 4 + r][nl] = acc[half * 2 + mtl][g][r];
            }
            __syncthreads();
            // phase B: kh=0 waves add theirs
            if (kh == 0) {
                #pragma unroll
                for (int mtl = 0; mtl < 2; ++mtl)
                    #pragma unroll
                    for (int g = 0; g < 4; ++g)
                        #pragma unroll
                        for (int r = 0; r < 4; ++r)
                            gplane[q][g][mtl * 16 + quad * 4 + r][nl] += acc[half * 2 + mtl][g][r];
            }
            __syncthreads();
            // phase C: combine q-partials, LSTM cell, write h (fragment order)
            if (tid < 128) {
                const int ml = tid >> 2;          // 0..31
                const int jg = tid & 3;
                const int m  = half * 32 + ml;
                const int jA = j0 + jg * 4;

                f32x4 vi = *(const f32x4*)&gplane[0][0][ml][jg*4] + *(const f32x4*)&gplane[1][0][ml][jg*4]
                         + *(const f32x4*)&gplane[2][0][ml][jg*4] + *(const f32x4*)&gplane[3][0][ml][jg*4];
                f32x4 vf = *(const f32x4*)&gplane[0][1][ml][jg*4] + *(const f32x4*)&gplane[1][1][ml][jg*4]
                         + *(const f32x4*)&gplane[2][1][ml][jg*4] + *(const f32x4*)&gplane[3][1][ml][jg*4];
                f32x4 vg = *(const f32x4*)&gplane[0][2][ml][jg*4] + *(const f32x4*)&gplane[1][2][ml][jg*4]
                         + *(const f32x4*)&gplane[2][2][ml][jg*4] + *(const f32x4*)&gplane[3][2][ml][jg*4];
                f32x4 vo = *(const f32x4*)&gplane[0][3][ml][jg*4] + *(const f32x4*)&gplane[1][3][ml][jg*4]
                         + *(const f32x4*)&gplane[2][3][ml][jg*4] + *(const f32x4*)&gplane[3][3][ml][jg*4];

                f32x4 bi = *(const f32x4*)&gbias[0][jg*4];
                f32x4 bf = *(const f32x4*)&gbias[1][jg*4];
                f32x4 bg = *(const f32x4*)&gbias[2][jg*4];
                f32x4 bo = *(const f32x4*)&gbias[3][jg*4];

                f32x4 c = *(const f32x4*)&cbuf[m][jg*4];
                f32x4 cn, hn;
                #pragma unroll
                for (int i = 0; i < 4; ++i) {
                    float gi = vi[i] + bi[i];
                    float gf = vf[i] + bf[i];
                    float gg = vg[i] + bg[i];
                    float go = vo[i] + bo[i];
                    cn[i] = sig_(gf) * c[i] + sig_(gi) * th_(gg);
                    hn[i] = sig_(go) * th_(cn[i]);
                }
                *(f32x4*)&cbuf[m][jg*4] = cn;

                int i_ = jA >> 5, qd = (jA >> 3) & 3, jj = jA & 7;
                size_t hoff = (size_t)(m >> 4) * 16384 + (size_t)i_ * 512 + qd * 128 + (m & 15) * 8 + jj;
                half4 h4;
                h4[0]=(_Float16)hn[0]; h4[1]=(_Float16)hn[1]; h4[2]=(_Float16)hn[2]; h4[3]=(_Float16)hn[3];
                llc_store_h4(hp + hoff, h4);   // write-through to IF (sc1)

                if (last) *(f32x4*)(out + (size_t)m * HID + jA) = hn;
            }
            __syncthreads();
        }

        // ---- end-of-step arrival (no waiting here; waits are at step start) ----
        asm volatile("s_waitcnt vmcnt(0)" ::: "memory");   // h sc1 stores acked at IF
        __syncthreads();
        if (tid == 0) {
            int a = __hip_atomic_fetch_add(&bar->arrive[layer][0], 1,
                        __ATOMIC_RELAXED, __HIP_MEMORY_SCOPE_AGENT) + 1;
            if (a == 64 * (t + 1))
                __hip_atomic_store(&bar->done[layer][0], t + 1,
                        __ATOMIC_RELAXED, __HIP_MEMORY_SCOPE_AGENT);
        }
    }
}

// ---------------------------------------------------------------------------
// Fallback: proven per-step kernel, used only if cooperative enqueue fails
// or the workspace is too small for write-once slabs.
// ---------------------------------------------------------------------------
__global__ __launch_bounds__(512) void k_step(
        int s,
        const _Float16* __restrict__ xpack,
        const _Float16* __restrict__ wpack,
        const float*    __restrict__ bias,
        _Float16*       __restrict__ hbuf,
        float*          __restrict__ cst,
        float*          __restrict__ out)
{
    const int layer = blockIdx.x >> 6;
    const int t = s - layer;
    if (t < 0 || t >= SEQ) return;

    __shared__ __align__(16) float gplane[4][4][32][16];

    const int tid  = threadIdx.x;
    const int wave = tid >> 6;
    const int q    = wave & 3;
    const int kh   = wave >> 2;
    const int lane = tid & 63;
    const int nl   = lane & 15;
    const int quad = lane >> 4;
    const int jblk = blockIdx.x & 63;
    const int j0   = jblk << 4;
    const size_t BH = (size_t)BATCH * HID;

    const _Float16* Abase;
    if (kh == 0) {
        Abase = (layer == 0) ? (xpack + (size_t)t * BH)
                             : (hbuf + ((size_t)(layer - 1) * 2 + (t & 1)) * BH);
    } else {
        Abase = hbuf + ((size_t)layer * 2 + ((t + 1) & 1)) * BH;
    }
    const _Float16* Ap = Abase + (size_t)q * 4096 + (size_t)lane * 8;
    const _Float16* Wp = wpack
        + ((((size_t)layer * 2 + kh) * 64 + jblk) * 4 + q) * 16384
        + (size_t)lane * 8;

    f32x4 acc[4][4];
    #pragma unroll
    for (int mt = 0; mt < 4; ++mt)
        #pragma unroll
        for (int g = 0; g < 4; ++g) acc[mt][g] = (f32x4){0,0,0,0};

    #pragma unroll
    for (int il = 0; il < 8; ++il) {
        half8 w0 = *(const half8*)(Wp + il * 2048 + 0 * 512);
        half8 w1 = *(const half8*)(Wp + il * 2048 + 1 * 512);
        half8 w2 = *(const half8*)(Wp + il * 2048 + 2 * 512);
        half8 w3 = *(const half8*)(Wp + il * 2048 + 3 * 512);
        #pragma unroll
        for (int mt = 0; mt < 4; ++mt) {
            half8 a = *(const half8*)(Ap + (size_t)mt * 16384 + il * 512);
            acc[mt][0] = __builtin_amdgcn_mfma_f32_16x16x32_f16(a, w0, acc[mt][0], 0,0,0);
            acc[mt][1] = __builtin_amdgcn_mfma_f32_16x16x32_f16(a, w1, acc[mt][1], 0,0,0);
            acc[mt][2] = __builtin_amdgcn_mfma_f32_16x16x32_f16(a, w2, acc[mt][2], 0,0,0);
            acc[mt][3] = __builtin_amdgcn_mfma_f32_16x16x32_f16(a, w3, acc[mt][3], 0,0,0);
        }
    }

    const float* bb = bias + (size_t)layer * 4 * HID;
    _Float16* hp = hbuf + ((size_t)layer * 2 + (t & 1)) * BH;
    const bool last = (layer == LAYERS - 1) && (t == SEQ - 1);

    #pragma unroll
    for (int half = 0; half < 2; ++half) {
        if (kh == 1) {
            #pragma unroll
            for (int mtl = 0; mtl < 2; ++mtl)
                #pragma unroll
                for (int g = 0; g < 4; ++g)
                    #pragma unroll
                    for (int r = 0; r < 4; ++r)
                        gplane[q][g][mtl * 16 + quad * 4 + r][nl] = acc[half * 2 + mtl][g][r];
        }
        __syncthreads();
        if (kh == 0) {
            #pragma unroll
            for (int mtl = 0; mtl < 2; ++mtl)
                #pragma unroll
                for (int g = 0; g < 4; ++g)
                    #pragma unroll
                    for (int r = 0; r < 4; ++r)
                        gplane[q][g][mtl * 16 + quad * 4 + r][nl] += acc[half * 2 + mtl][g][r];
        }
        __syncthreads();
        if (tid < 128) {
            const int ml = tid >> 2;
            const int jg = tid & 3;
            const int m  = half * 32 + ml;
            const int jA = j0 + jg * 4;

            f32x4 vi = *(const f32x4*)&gplane[0][0][ml][jg*4] + *(const f32x4*)&gplane[1][0][ml][jg*4]
                     + *(const f32x4*)&gplane[2][0][ml][jg*4] + *(const f32x4*)&gplane[3][0][ml][jg*4];
            f32x4 vf = *(const f32x4*)&gplane[0][1][ml][jg*4] + *(const f32x4*)&gplane[1][1][ml][jg*4]
                     + *(const f32x4*)&gplane[2][1][ml][jg*4] + *(const f32x4*)&gplane[3][1][ml][jg*4];
            f32x4 vg = *(const f32x4*)&gplane[0][2][ml][jg*4] + *(const f32x4*)&gplane[1][2][ml][jg*4]
                     + *(const f32x4*)&gplane[2][2][ml][jg*4] + *(const f32x4*)&gplane[3][2][ml][jg*4];
            f32x4 vo = *(const f32x4*)&gplane[0][3][ml][jg*4] + *(const f32x4*)&gplane[1][3][ml][jg*4]
                     + *(const f32x4*)&gplane[2][3][ml][jg*4] + *(const f32x4*)&gplane[3][3][ml][jg*4];

            f32x4 bi = *(const f32x4*)(bb + 0 * HID + jA);
            f32x4 bf = *(const f32x4*)(bb + 1 * HID + jA);
            f32x4 bg = *(const f32x4*)(bb + 2 * HID + jA);
            f32x4 bo = *(const f32x4*)(bb + 3 * HID + jA);

            float* cp = cst + (size_t)layer * BH + (size_t)m * HID + jA;
            f32x4 c = *(const f32x4*)cp;
            f32x4 cn, hn;
            #pragma unroll
            for (int i = 0; i < 4; ++i) {
                float gi = vi[i] + bi[i];
                float gf = vf[i] + bf[i];
                float gg = vg[i] + bg[i];
                float go = vo[i] + bo[i];
                cn[i] = sig_(gf) * c[i] + sig_(gi) * th_(gg);
                hn[i] = sig_(go) * th_(cn[i]);
            }
            *(f32x4*)cp = cn;

            int i_ = jA >> 5, qd = (jA >> 3) & 3, jj = jA & 7;
            size_t hoff = (size_t)(m >> 4) * 16384 + (size_t)i_ * 512 + qd * 128 + (m & 15) * 8 + jj;
            half4 h4;
            h4[0]=(_Float16)hn[0]; h4[1]=(_Float16)hn[1]; h4[2]=(_Float16)hn[2]; h4[3]=(_Float16)hn[3];
            *(half4*)(hp + hoff) = h4;

            if (last) *(f32x4*)(out + (size_t)m * HID + jA) = hn;
        }
        __syncthreads();
    }
}

extern "C" void kernel_launch(void* const* d_in, const int* in_sizes, int n_in,
                              void* d_out, int out_size, void* d_ws, size_t ws_size,
                              hipStream_t stream) {
    const float* x32   = (const float*)d_in[0];
    const float* wih32 = (const float*)d_in[1];
    const float* whh32 = (const float*)d_in[2];
    const float* bih   = (const float*)d_in[3];
    const float* bhh   = (const float*)d_in[4];
    (void)in_sizes; (void)n_in; (void)out_size;

    const size_t BH = (size_t)BATCH * HID;
    char* ws = (char*)d_ws;
    size_t off = 0;
    _Float16* hpar  = (_Float16*)(ws + off); off += (size_t)LAYERS * 2 * BH * 2;      // 1 MB (fallback)
    float*    cst   = (float*)   (ws + off); off += (size_t)LAYERS * BH * 4;          // 1 MB (fallback)
    BarSt*    bar   = (BarSt*)   (ws + off); off += sizeof(BarSt);
    off = (off + 255) & ~(size_t)255;
    size_t zero_bytes = off;                      // hpar + cst + sync state
    float*    bias  = (float*)   (ws + off); off += (size_t)LAYERS * 4 * HID * 4;     // 64 KB
    _Float16* wpack = (_Float16*)(ws + off); off += (size_t)2 * LAYERS * 4 * HID * HID * 2; // 67 MB
    _Float16* xpack = (_Float16*)(ws + off); off += (size_t)SEQ * BH * 2;             // 33.5 MB
    _Float16* hfull = (_Float16*)(ws + off);
    size_t full_need = off + (size_t)(SEQ * LAYERS + 1) * BH * 2;                      // +131 MB
    const int can_persist = (ws_size >= full_need) ? 1 : 0;

    hipMemsetAsync(ws, 0, zero_bytes, stream);
    if (can_persist) hipMemsetAsync(hfull, 0, BH * 2, stream);  // zero slab 0 (t=-1 state)
    k_bias<<<(LAYERS * 4 * HID + 255) / 256, 256, 0, stream>>>(bih, bhh, bias);
    k_packw<<<(1u << 22) / 256, 256, 0, stream>>>(wih32, whh32, wpack);
    k_packx<<<(1u << 21) / 256, 256, 0, stream>>>(x32, xpack);

    hipError_t cerr = hipErrorUnknown;
    if (can_persist) {
        float* outp = (float*)d_out;
        _Float16* hfull_arg = hfull;
        void* kargs[] = { (void*)&xpack, (void*)&wpack, (void*)&bih, (void*)&bhh,
                          (void*)&hfull_arg, (void*)&bar, (void*)&outp };
        cerr = hipLaunchCooperativeKernel(
            k_persist, dim3(LAYERS * 64), dim3(512), kargs, 0u, stream);
    }

    if (cerr != hipSuccess) {
        for (int s = 0; s < SEQ + LAYERS - 1; ++s)
            k_step<<<LAYERS * 64, 512, 0, stream>>>(
                s, xpack, wpack, bias, hpar, cst, (float*)d_out);
    }
}

// Round 6
// 2450.115 us; speedup vs baseline: 1.1652x; 1.1652x over previous
//
#include <hip/hip_runtime.h>

#define LAYERS 4
#define BATCH  64
#define SEQ    256
#define HID    1024

typedef _Float16 half8 __attribute__((ext_vector_type(8)));
typedef _Float16 half4 __attribute__((ext_vector_type(4)));
typedef float    f32x4 __attribute__((ext_vector_type(4)));
typedef unsigned long long u64;

__device__ __forceinline__ float sig_(float x) { return 1.0f / (1.0f + __expf(-x)); }
__device__ __forceinline__ float th_(float x)  { return 2.0f / (1.0f + __expf(-2.0f * x)) - 1.0f; }

// sc1 (LLC-coherent) store: relaxed agent-scope atomic -> write-through to the
// Infinity Cache (coherence point), bypassing the non-coherent per-XCD L2.
__device__ __forceinline__ void llc_store_h4(_Float16* p, half4 v) {
    union { half4 h; u64 u; } cv; cv.h = v;
    __hip_atomic_store((u64*)p, cv.u, __ATOMIC_RELAXED, __HIP_MEMORY_SCOPE_AGENT);
}

// Per-layer tree sync state. Each counter on its own 64B line.
//  arrive8[l][o]: octet arrival counters (8 blocks each, cumulative)
//  rootL[l]:      octet-completion counter (8 leaders, cumulative)
//  done8[l][o]:   8 broadcast copies of "steps completed by layer l"
struct BarSt {
    int arrive8[LAYERS][8][16];
    int rootL[LAYERS][16];
    int done8[LAYERS][8][16];
};

__global__ void k_bias(const float* __restrict__ bih, const float* __restrict__ bhh,
                       float* __restrict__ bias) {
    int i = blockIdx.x * blockDim.x + threadIdx.x;
    if (i < LAYERS * 4 * HID) bias[i] = bih[i] + bhh[i];
}

// Pack weights fp32 -> f16, gate-major per-wave fragment order.
__global__ void k_packw(const float* __restrict__ wih32, const float* __restrict__ whh32,
                        _Float16* __restrict__ wpack) {
    unsigned c = blockIdx.x * blockDim.x + threadIdx.x;   // < 2^22
    int lane = c & 63, g = (c >> 6) & 3, il = (c >> 8) & 7, q = (c >> 11) & 3;
    int jblk = (c >> 13) & 63, kh = (c >> 19) & 1, l = (int)(c >> 20);
    const float* src = (kh ? whh32 : wih32)
        + ((size_t)l * 4 * HID + (size_t)g * HID + jblk * 16 + (lane & 15)) * HID
        + (q * 8 + il) * 32 + (lane >> 4) * 8;
    f32x4 a = *(const f32x4*)src;
    f32x4 b = *(const f32x4*)(src + 4);
    half8 d;
    d[0]=(_Float16)a[0]; d[1]=(_Float16)a[1]; d[2]=(_Float16)a[2]; d[3]=(_Float16)a[3];
    d[4]=(_Float16)b[0]; d[5]=(_Float16)b[1]; d[6]=(_Float16)b[2]; d[7]=(_Float16)b[3];
    *(half8*)(wpack + (size_t)c * 8) = d;
}

// Pack x fp32 [B,T,H] -> f16 fragment order per t.
__global__ void k_packx(const float* __restrict__ x32, _Float16* __restrict__ xpack) {
    unsigned c = blockIdx.x * blockDim.x + threadIdx.x;   // < 2^21
    int lane = c & 63, i = (c >> 6) & 31, mt = (c >> 11) & 3, t = (int)(c >> 13);
    int m = mt * 16 + (lane & 15);
    int k = i * 32 + (lane >> 4) * 8;
    const float* src = x32 + ((size_t)m * SEQ + t) * HID + k;
    f32x4 a = *(const f32x4*)src;
    f32x4 b = *(const f32x4*)(src + 4);
    half8 d;
    d[0]=(_Float16)a[0]; d[1]=(_Float16)a[1]; d[2]=(_Float16)a[2]; d[3]=(_Float16)a[3];
    d[4]=(_Float16)b[0]; d[5]=(_Float16)b[1]; d[6]=(_Float16)b[2]; d[7]=(_Float16)b[3];
    *(half8*)(xpack + (size_t)c * 8) = d;
}

// ---------------------------------------------------------------------------
// Persistent kernel, per-layer dataflow sync, single-pass reduction:
//  - weights in registers; c-state + bias in LDS
//  - h slabs WRITE-ONCE (hfull[t*L + l + 1], slot 0 = zeros); writers sc1-store
//    (write-through to IF), readers plain L2-cached 16B loads (no address is
//    written twice in a run -> no stale L2 line possible)
//  - BOTH m-halves deposited into a double reduction plane -> 3 barriers/step
//    (was 7), phase C runs on 4 waves (256 threads)
//  - 8-ary tree arrival + 8 done broadcast lines: ~3 low-contention IF RTTs
// 256 blocks (1/CU) x 512 threads: layer = bid>>6, 16 cols; wave = (kh, q).
// ---------------------------------------------------------------------------
__global__ __launch_bounds__(512, 1) void k_persist(
        const _Float16* __restrict__ xpack,
        const _Float16* __restrict__ wpack,
        const float*    __restrict__ bih,
        const float*    __restrict__ bhh,
        _Float16*       __restrict__ hfull,  // [SEQ*L+1][BH] f16, fragment order
        BarSt*          __restrict__ bar,
        float*          __restrict__ out)    // [B, H] fp32
{
    const int layer = blockIdx.x >> 6;
    const int jblk  = blockIdx.x & 63;
    const int j0    = jblk << 4;
    const int oct   = jblk >> 3;              // 0..7 octet within layer
    const int tid   = threadIdx.x;
    const int wave  = tid >> 6;
    const int q     = wave & 3;
    const int kh    = wave >> 2;
    const int lane  = tid & 63;
    const int nl    = lane & 15;
    const int quad  = lane >> 4;
    const size_t BH = (size_t)BATCH * HID;

    // double reduction plane: [m-half][q][g][row][pad20] = 80 KB, 2-way max
    __shared__ __align__(16) float gplane[2][4][4][32][20];
    __shared__ __align__(16) float cbuf[64][16];           // cell state
    __shared__ __align__(16) float gbias[4][16];           // bih+bhh slice

    for (int i = tid; i < 64 * 16; i += 512) ((float*)cbuf)[i] = 0.0f;
    if (tid < 64) {
        int g = tid >> 4, col = tid & 15;
        size_t bidx = (size_t)layer * 4 * HID + (size_t)g * HID + j0 + col;
        gbias[g][col] = bih[bidx] + bhh[bidx];
    }

    // weights -> registers, once (8 il x 4 gates x half8 = 128 regs/lane)
    const _Float16* Wp = wpack
        + ((((size_t)layer * 2 + kh) * 64 + jblk) * 4 + q) * 16384
        + (size_t)lane * 8;
    half8 wreg[8][4];
    #pragma unroll
    for (int il = 0; il < 8; ++il)
        #pragma unroll
        for (int g = 0; g < 4; ++g)
            wreg[il][g] = *(const half8*)(Wp + il * 2048 + g * 512);

    __syncthreads();

    const bool lastlayer = (layer == LAYERS - 1);

    for (int t = 0; t < SEQ; ++t) {
        // ---- wave-granularity dataflow waits (8 pollers per done line) ----
        if (lane == 0) {
            if (kh == 0) {
                if (layer > 0) {
                    while (__hip_atomic_load(&bar->done8[layer - 1][oct][0], __ATOMIC_RELAXED,
                                             __HIP_MEMORY_SCOPE_AGENT) < t + 1)
                        __builtin_amdgcn_s_sleep(1);
                }
            } else {
                if (t > 0) {
                    while (__hip_atomic_load(&bar->done8[layer][oct][0], __ATOMIC_RELAXED,
                                             __HIP_MEMORY_SCOPE_AGENT) < t)
                        __builtin_amdgcn_s_sleep(1);
                }
            }
        }
        __builtin_amdgcn_sched_barrier(0);
        asm volatile("" ::: "memory");

        // A operand base (fragment-packed), this wave's K-quarter
        const _Float16* Abase;
        if (kh == 0) {
            Abase = (layer == 0)
                ? (xpack + (size_t)t * BH)
                : (hfull + ((size_t)t * LAYERS + layer) * BH);       // (l-1, t)
        } else {
            Abase = hfull + (t == 0 ? (size_t)0
                                    : ((size_t)(t - 1) * LAYERS + layer + 1)) * BH;
        }
        const _Float16* Ap = Abase + (size_t)q * 4096 + (size_t)lane * 8;

        f32x4 acc[4][4];   // [mt][g]
        #pragma unroll
        for (int mt = 0; mt < 4; ++mt)
            #pragma unroll
            for (int g = 0; g < 4; ++g) acc[mt][g] = (f32x4){0,0,0,0};

        #pragma unroll
        for (int il = 0; il < 8; ++il) {
            #pragma unroll
            for (int mt = 0; mt < 4; ++mt) {
                half8 a = *(const half8*)(Ap + (size_t)mt * 16384 + il * 512);
                acc[mt][0] = __builtin_amdgcn_mfma_f32_16x16x32_f16(a, wreg[il][0], acc[mt][0], 0,0,0);
                acc[mt][1] = __builtin_amdgcn_mfma_f32_16x16x32_f16(a, wreg[il][1], acc[mt][1], 0,0,0);
                acc[mt][2] = __builtin_amdgcn_mfma_f32_16x16x32_f16(a, wreg[il][2], acc[mt][2], 0,0,0);
                acc[mt][3] = __builtin_amdgcn_mfma_f32_16x16x32_f16(a, wreg[il][3], acc[mt][3], 0,0,0);
            }
        }

        _Float16* hp = hfull + ((size_t)t * LAYERS + layer + 1) * BH;
        const bool last = lastlayer && (t == SEQ - 1);

        // phase A: kh=1 waves deposit BOTH halves
        if (kh == 1) {
            #pragma unroll
            for (int mt = 0; mt < 4; ++mt)
                #pragma unroll
                for (int g = 0; g < 4; ++g)
                    #pragma unroll
                    for (int r = 0; r < 4; ++r) {
                        int rm = mt * 16 + quad * 4 + r;   // 0..63
                        gplane[rm >> 5][q][g][rm & 31][nl] = acc[mt][g][r];
                    }
        }
        __syncthreads();
        // phase B: kh=0 waves add theirs (both halves)
        if (kh == 0) {
            #pragma unroll
            for (int mt = 0; mt < 4; ++mt)
                #pragma unroll
                for (int g = 0; g < 4; ++g)
                    #pragma unroll
                    for (int r = 0; r < 4; ++r) {
                        int rm = mt * 16 + quad * 4 + r;
                        gplane[rm >> 5][q][g][rm & 31][nl] += acc[mt][g][r];
                    }
        }
        __syncthreads();
        // phase C: 256 threads, each one (m, 4-col group): combine q-partials,
        // LSTM cell, write h (fragment order)
        if (tid < 256) {
            const int m  = tid >> 2;          // 0..63
            const int hb = m >> 5;
            const int ml = m & 31;
            const int jg = tid & 3;
            const int jA = j0 + jg * 4;

            f32x4 vi = *(const f32x4*)&gplane[hb][0][0][ml][jg*4] + *(const f32x4*)&gplane[hb][1][0][ml][jg*4]
                     + *(const f32x4*)&gplane[hb][2][0][ml][jg*4] + *(const f32x4*)&gplane[hb][3][0][ml][jg*4];
            f32x4 vf = *(const f32x4*)&gplane[hb][0][1][ml][jg*4] + *(const f32x4*)&gplane[hb][1][1][ml][jg*4]
                     + *(const f32x4*)&gplane[hb][2][1][ml][jg*4] + *(const f32x4*)&gplane[hb][3][1][ml][jg*4];
            f32x4 vg = *(const f32x4*)&gplane[hb][0][2][ml][jg*4] + *(const f32x4*)&gplane[hb][1][2][ml][jg*4]
                     + *(const f32x4*)&gplane[hb][2][2][ml][jg*4] + *(const f32x4*)&gplane[hb][3][2][ml][jg*4];
            f32x4 vo = *(const f32x4*)&gplane[hb][0][3][ml][jg*4] + *(const f32x4*)&gplane[hb][1][3][ml][jg*4]
                     + *(const f32x4*)&gplane[hb][2][3][ml][jg*4] + *(const f32x4*)&gplane[hb][3][3][ml][jg*4];

            f32x4 bi = *(const f32x4*)&gbias[0][jg*4];
            f32x4 bf = *(const f32x4*)&gbias[1][jg*4];
            f32x4 bg = *(const f32x4*)&gbias[2][jg*4];
            f32x4 bo = *(const f32x4*)&gbias[3][jg*4];

            f32x4 c = *(const f32x4*)&cbuf[m][jg*4];
            f32x4 cn, hn;
            #pragma unroll
            for (int i = 0; i < 4; ++i) {
                float gi = vi[i] + bi[i];
                float gf = vf[i] + bf[i];
                float gg = vg[i] + bg[i];
                float go = vo[i] + bo[i];
                cn[i] = sig_(gf) * c[i] + sig_(gi) * th_(gg);
                hn[i] = sig_(go) * th_(cn[i]);
            }
            *(f32x4*)&cbuf[m][jg*4] = cn;

            int i_ = jA >> 5, qd = (jA >> 3) & 3, jj = jA & 7;
            size_t hoff = (size_t)(m >> 4) * 16384 + (size_t)i_ * 512 + qd * 128 + (m & 15) * 8 + jj;
            half4 h4;
            h4[0]=(_Float16)hn[0]; h4[1]=(_Float16)hn[1]; h4[2]=(_Float16)hn[2]; h4[3]=(_Float16)hn[3];
            llc_store_h4(hp + hoff, h4);   // write-through to IF (sc1)

            if (last) *(f32x4*)(out + (size_t)m * HID + jA) = hn;
        }

        // ---- end of step: drain h stores, then tree arrival ----
        asm volatile("s_waitcnt vmcnt(0)" ::: "memory");   // sc1 stores acked at IF
        __syncthreads();                                    // also guards gplane reuse
        if (tid == 0) {
            int a = __hip_atomic_fetch_add(&bar->arrive8[layer][oct][0], 1,
                        __ATOMIC_RELAXED, __HIP_MEMORY_SCOPE_AGENT) + 1;
            if (a == 8 * (t + 1)) {            // octet complete for step t
                int r = __hip_atomic_fetch_add(&bar->rootL[layer][0], 1,
                            __ATOMIC_RELAXED, __HIP_MEMORY_SCOPE_AGENT) + 1;
                if (r == 8 * (t + 1)) {        // layer complete for step t
                    #pragma unroll
                    for (int o = 0; o < 8; ++o)
                        __hip_atomic_store(&bar->done8[layer][o][0], t + 1,
                                __ATOMIC_RELAXED, __HIP_MEMORY_SCOPE_AGENT);
                }
            }
        }
    }
}

// ---------------------------------------------------------------------------
// Fallback: proven per-step kernel, used only if cooperative enqueue fails
// or the workspace is too small for write-once slabs.
// ---------------------------------------------------------------------------
__global__ __launch_bounds__(512) void k_step(
        int s,
        const _Float16* __restrict__ xpack,
        const _Float16* __restrict__ wpack,
        const float*    __restrict__ bias,
        _Float16*       __restrict__ hbuf,
        float*          __restrict__ cst,
        float*          __restrict__ out)
{
    const int layer = blockIdx.x >> 6;
    const int t = s - layer;
    if (t < 0 || t >= SEQ) return;

    __shared__ __align__(16) float gplane[4][4][32][16];

    const int tid  = threadIdx.x;
    const int wave = tid >> 6;
    const int q    = wave & 3;
    const int kh   = wave >> 2;
    const int lane = tid & 63;
    const int nl   = lane & 15;
    const int quad = lane >> 4;
    const int jblk = blockIdx.x & 63;
    const int j0   = jblk << 4;
    const size_t BH = (size_t)BATCH * HID;

    const _Float16* Abase;
    if (kh == 0) {
        Abase = (layer == 0) ? (xpack + (size_t)t * BH)
                             : (hbuf + ((size_t)(layer - 1) * 2 + (t & 1)) * BH);
    } else {
        Abase = hbuf + ((size_t)layer * 2 + ((t + 1) & 1)) * BH;
    }
    const _Float16* Ap = Abase + (size_t)q * 4096 + (size_t)lane * 8;
    const _Float16* Wp = wpack
        + ((((size_t)layer * 2 + kh) * 64 + jblk) * 4 + q) * 16384
        + (size_t)lane * 8;

    f32x4 acc[4][4];
    #pragma unroll
    for (int mt = 0; mt < 4; ++mt)
        #pragma unroll
        for (int g = 0; g < 4; ++g) acc[mt][g] = (f32x4){0,0,0,0};

    #pragma unroll
    for (int il = 0; il < 8; ++il) {
        half8 w0 = *(const half8*)(Wp + il * 2048 + 0 * 512);
        half8 w1 = *(const half8*)(Wp + il * 2048 + 1 * 512);
        half8 w2 = *(const half8*)(Wp + il * 2048 + 2 * 512);
        half8 w3 = *(const half8*)(Wp + il * 2048 + 3 * 512);
        #pragma unroll
        for (int mt = 0; mt < 4; ++mt) {
            half8 a = *(const half8*)(Ap + (size_t)mt * 16384 + il * 512);
            acc[mt][0] = __builtin_amdgcn_mfma_f32_16x16x32_f16(a, w0, acc[mt][0], 0,0,0);
            acc[mt][1] = __builtin_amdgcn_mfma_f32_16x16x32_f16(a, w1, acc[mt][1], 0,0,0);
            acc[mt][2] = __builtin_amdgcn_mfma_f32_16x16x32_f16(a, w2, acc[mt][2], 0,0,0);
            acc[mt][3] = __builtin_amdgcn_mfma_f32_16x16x32_f16(a, w3, acc[mt][3], 0,0,0);
        }
    }

    const float* bb = bias + (size_t)layer * 4 * HID;
    _Float16* hp = hbuf + ((size_t)layer * 2 + (t & 1)) * BH;
    const bool last = (layer == LAYERS - 1) && (t == SEQ - 1);

    #pragma unroll
    for (int half = 0; half < 2; ++half) {
        if (kh == 1) {
            #pragma unroll
            for (int mtl = 0; mtl < 2; ++mtl)
                #pragma unroll
                for (int g = 0; g < 4; ++g)
                    #pragma unroll
                    for (int r = 0; r < 4; ++r)
                        gplane[q][g][mtl * 16 + quad * 4 + r][nl] = acc[half * 2 + mtl][g][r];
        }
        __syncthreads();
        if (kh == 0) {
            #pragma unroll
            for (int mtl = 0; mtl < 2; ++mtl)
                #pragma unroll
                for (int g = 0; g < 4; ++g)
                    #pragma unroll
                    for (int r = 0; r < 4; ++r)
                        gplane[q][g][mtl * 16 + quad * 4 + r][nl] += acc[half * 2 + mtl][g][r];
        }
        __syncthreads();
        if (tid < 128) {
            const int ml = tid >> 2;
            const int jg = tid & 3;
            const int m  = half * 32 + ml;
            const int jA = j0 + jg * 4;

            f32x4 vi = *(const f32x4*)&gplane[0][0][ml][jg*4] + *(const f32x4*)&gplane[1][0][ml][jg*4]
                     + *(const f32x4*)&gplane[2][0][ml][jg*4] + *(const f32x4*)&gplane[3][0][ml][jg*4];
            f32x4 vf = *(const f32x4*)&gplane[0][1][ml][jg*4] + *(const f32x4*)&gplane[1][1][ml][jg*4]
                     + *(const f32x4*)&gplane[2][1][ml][jg*4] + *(const f32x4*)&gplane[3][1][ml][jg*4];
            f32x4 vg = *(const f32x4*)&gplane[0][2][ml][jg*4] + *(const f32x4*)&gplane[1][2][ml][jg*4]
                     + *(const f32x4*)&gplane[2][2][ml][jg*4] + *(const f32x4*)&gplane[3][2][ml][jg*4];
            f32x4 vo = *(const f32x4*)&gplane[0][3][ml][jg*4] + *(const f32x4*)&gplane[1][3][ml][jg*4]
                     + *(const f32x4*)&gplane[2][3][ml][jg*4] + *(const f32x4*)&gplane[3][3][ml][jg*4];

            f32x4 bi = *(const f32x4*)(bb + 0 * HID + jA);
            f32x4 bf = *(const f32x4*)(bb + 1 * HID + jA);
            f32x4 bg = *(const f32x4*)(bb + 2 * HID + jA);
            f32x4 bo = *(const f32x4*)(bb + 3 * HID + jA);

            float* cp = cst + (size_t)layer * BH + (size_t)m * HID + jA;
            f32x4 c = *(const f32x4*)cp;
            f32x4 cn, hn;
            #pragma unroll
            for (int i = 0; i < 4; ++i) {
                float gi = vi[i] + bi[i];
                float gf = vf[i] + bf[i];
                float gg = vg[i] + bg[i];
                float go = vo[i] + bo[i];
                cn[i] = sig_(gf) * c[i] + sig_(gi) * th_(gg);
                hn[i] = sig_(go) * th_(cn[i]);
            }
            *(f32x4*)cp = cn;

            int i_ = jA >> 5, qd = (jA >> 3) & 3, jj = jA & 7;
            size_t hoff = (size_t)(m >> 4) * 16384 + (size_t)i_ * 512 + qd * 128 + (m & 15) * 8 + jj;
            half4 h4;
            h4[0]=(_Float16)hn[0]; h4[1]=(_Float16)hn[1]; h4[2]=(_Float16)hn[2]; h4[3]=(_Float16)hn[3];
            *(half4*)(hp + hoff) = h4;

            if (last) *(f32x4*)(out + (size_t)m * HID + jA) = hn;
        }
        __syncthreads();
    }
}

extern "C" void kernel_launch(void* const* d_in, const int* in_sizes, int n_in,
                              void* d_out, int out_size, void* d_ws, size_t ws_size,
                              hipStream_t stream) {
    const float* x32   = (const float*)d_in[0];
    const float* wih32 = (const float*)d_in[1];
    const float* whh32 = (const float*)d_in[2];
    const float* bih   = (const float*)d_in[3];
    const float* bhh   = (const float*)d_in[4];
    (void)in_sizes; (void)n_in; (void)out_size;

    const size_t BH = (size_t)BATCH * HID;
    char* ws = (char*)d_ws;
    size_t off = 0;
    _Float16* hpar  = (_Float16*)(ws + off); off += (size_t)LAYERS * 2 * BH * 2;      // 1 MB (fallback)
    float*    cst   = (float*)   (ws + off); off += (size_t)LAYERS * BH * 4;          // 1 MB (fallback)
    BarSt*    bar   = (BarSt*)   (ws + off); off += sizeof(BarSt);
    off = (off + 255) & ~(size_t)255;
    size_t zero_bytes = off;                      // hpar + cst + sync state
    float*    bias  = (float*)   (ws + off); off += (size_t)LAYERS * 4 * HID * 4;     // 64 KB
    _Float16* wpack = (_Float16*)(ws + off); off += (size_t)2 * LAYERS * 4 * HID * HID * 2; // 67 MB
    _Float16* xpack = (_Float16*)(ws + off); off += (size_t)SEQ * BH * 2;             // 33.5 MB
    _Float16* hfull = (_Float16*)(ws + off);
    size_t full_need = off + (size_t)(SEQ * LAYERS + 1) * BH * 2;                      // +131 MB
    const int can_persist = (ws_size >= full_need) ? 1 : 0;

    hipMemsetAsync(ws, 0, zero_bytes, stream);
    if (can_persist) hipMemsetAsync(hfull, 0, BH * 2, stream);  // zero slab 0 (t=-1 state)
    k_bias<<<(LAYERS * 4 * HID + 255) / 256, 256, 0, stream>>>(bih, bhh, bias);
    k_packw<<<(1u << 22) / 256, 256, 0, stream>>>(wih32, whh32, wpack);
    k_packx<<<(1u << 21) / 256, 256, 0, stream>>>(x32, xpack);

    hipError_t cerr = hipErrorUnknown;
    if (can_persist) {
        float* outp = (float*)d_out;
        _Float16* hfull_arg = hfull;
        void* kargs[] = { (void*)&xpack, (void*)&wpack, (void*)&bih, (void*)&bhh,
                          (void*)&hfull_arg, (void*)&bar, (void*)&outp };
        cerr = hipLaunchCooperativeKernel(
            k_persist, dim3(LAYERS * 64), dim3(512), kargs, 0u, stream);
    }

    if (cerr != hipSuccess) {
        for (int s = 0; s < SEQ + LAYERS - 1; ++s)
            k_step<<<LAYERS * 64, 512, 0, stream>>>(
                s, xpack, wpack, bias, hpar, cst, (float*)d_out);
    }
}